// Round 12
// baseline (203.177 us; speedup 1.0000x reference)
//
#include <hip/hip_runtime.h>
#include <hip/hip_bf16.h>

typedef unsigned short u16;
typedef __attribute__((ext_vector_type(8))) short short8;
typedef __attribute__((ext_vector_type(4))) float f32x4;
typedef __attribute__((ext_vector_type(4))) unsigned short u16x4;

#define LOG2E 1.44269504088896340736f
// Q pre-scale: 1/sqrt(64) * log2(e), folded into the QKV gemm epilogue
#define QSCALE_F 0.18033688011112042f

// ---- helpers ---------------------------------------------------------------

__device__ __forceinline__ void gl_lds16(const void* g, void* l) {
  __builtin_amdgcn_global_load_lds(
      (__attribute__((address_space(1))) void*)g,
      (__attribute__((address_space(3))) void*)l, 16, 0, 0);
}

__device__ __forceinline__ float exp2_fast(float x) {
#if __has_builtin(__builtin_amdgcn_exp2f)
  return __builtin_amdgcn_exp2f(x);  // bare v_exp_f32
#else
  return exp2f(x);
#endif
}

__device__ __forceinline__ u16 f2bf(float f) {
  union { float f; unsigned int i; } v;
  v.f = f;
  unsigned int r = v.i + 0x7fffu + ((v.i >> 16) & 1u);  // RNE
  return (u16)(r >> 16);
}

__device__ __forceinline__ unsigned int pack_bf2(float lo, float hi) {
  union { __hip_bfloat162 h2; unsigned int u; } c;
  c.h2 = __float22bfloat162_rn(make_float2(lo, hi));
  return c.u;
}

// ---- fused prep: x->bf16 cvt + both weight transposes ----------------------

__global__ __launch_bounds__(256) void prep_kernel(
    const float4* __restrict__ x, u16x4* __restrict__ xb,
    const float* __restrict__ Wqkv, u16* __restrict__ WqkvT,
    const float* __restrict__ Wout, u16* __restrict__ WoutT) {
  __shared__ u16 t[64][65];
  int bid = blockIdx.x, tid = threadIdx.x;
  if (bid < 4096) {
    int i = bid * 256 + tid;
    float4 v = x[i];
    u16x4 o;
    o.x = f2bf(v.x); o.y = f2bf(v.y); o.z = f2bf(v.z); o.w = f2bf(v.w);
    xb[i] = o;
    return;
  }
  const float* W;
  u16* WT;
  int K = 1024, N, bxx, byy;
  if (bid < 4864) {
    int tt = bid - 4096;
    W = Wqkv; WT = WqkvT; N = 3072; bxx = tt % 48; byy = tt / 48;
  } else {
    int tt = bid - 4864;
    W = Wout; WT = WoutT; N = 1024; bxx = tt % 16; byy = tt / 16;
  }
  int r0 = byy * 64, c0 = bxx * 64;
  int tx = tid & 63, ty = tid >> 6;
  for (int r = ty; r < 64; r += 4)
    t[r][tx] = f2bf(W[(size_t)(r0 + r) * N + c0 + tx]);
  __syncthreads();
  for (int r = ty; r < 64; r += 4)
    WT[(size_t)(c0 + r) * K + r0 + tx] = t[tx][r];
}

// ---- gemm8: BMxBN tile, BK=64, 8 waves (2Mx4N), double-buffered LDS --------
// One barrier per K-tile: vmcnt(0); s_barrier; DMA tile t+1; compute tile t.
// DMA uses swizzle-precomputed SOURCE cols so lane-linear writes land
// XOR-swizzled; frag reads use addr ^ ((row&7)*8) -> conflict-free b128.
// Grids are exactly 256 blocks; bijective XCD swizzle (bid&7)*32+(bid>>3).
// QSC: scale output cols < 1024 (the Q block of the QKV gemm) by QSCALE_F so
// flash's softmax needs no per-element fmaf (acc-init -16 supplies the shift).

template <bool OUT_F32, int BM, int BN, bool QSC>
__global__ __launch_bounds__(512, 1) void gemm8_kernel(
    const u16* __restrict__ A, const u16* __restrict__ Bt,
    const float* __restrict__ bias, void* __restrict__ Cout,
    int M, int N, int K) {
  constexpr int MI = BM / 32;          // M frags per wave (BM/2 rows / 16)
  constexpr int NJ = BN / 64;          // N frags per wave (BN/4 cols / 16)
  constexpr int CH_A = BM / 8;         // 8-row staging chunks of A
  constexpr int CH_B = BN / 8;
  constexpr int PER_W = (CH_A + CH_B) / 8;  // chunks per wave
  __shared__ u16 LDS[2][(BM + BN) * 64];
  int tid = threadIdx.x;
  int w = tid >> 6, lane = tid & 63, l15 = lane & 15, quad = lane >> 4;
  // XCD-aware bijective swizzle (nwg == 256, divisible by 8)
  int bid = blockIdx.y * gridDim.x + blockIdx.x;
  int swz = ((bid & 7) << 5) | (bid >> 3);
  int bx = swz % gridDim.x, by = swz / gridDim.x;
  int m0 = by * BM, n0 = bx * BN;
  int wm = (w & 1) * (BM / 2), wn = (w >> 1) * (BN / 4);

  f32x4 acc[MI][NJ];
#pragma unroll
  for (int i = 0; i < MI; ++i)
#pragma unroll
    for (int j = 0; j < NJ; ++j) {
      f32x4 z = {0.f, 0.f, 0.f, 0.f};
      acc[i][j] = z;
    }

  int r8 = lane >> 3;                 // row within 8-row chunk
  int sw = ((lane & 7) ^ r8) * 8;     // swizzled source col (u16)

  // per-wave staging chunk list (fully unrolled -> stays in registers)
  const u16* srcp[PER_W];
  int dsto[PER_W];
#pragma unroll
  for (int i = 0; i < PER_W; ++i) {
    int c = w * PER_W + i;
    if (c < CH_A) {
      srcp[i] = A + (size_t)(m0 + c * 8 + r8) * K + sw;
    } else {
      srcp[i] = Bt + (size_t)(n0 + (c - CH_A) * 8 + r8) * K + sw;
    }
    dsto[i] = c * 512;
  }

  int nt = K >> 6;
  // prologue: stage tile 0 into buf 0
#pragma unroll
  for (int i = 0; i < PER_W; ++i) gl_lds16(srcp[i], &LDS[0][dsto[i]]);

  for (int t = 0; t < nt; ++t) {
    asm volatile("s_waitcnt vmcnt(0)" ::: "memory");
    __builtin_amdgcn_s_barrier();
    asm volatile("" ::: "memory");
    int cur = t & 1;
    if (t + 1 < nt) {
      int koff = (t + 1) << 6;
#pragma unroll
      for (int i = 0; i < PER_W; ++i)
        gl_lds16(srcp[i] + koff, &LDS[cur ^ 1][dsto[i]]);
    }
    const u16* As = &LDS[cur][0];
    const u16* Bs = &LDS[cur][CH_A * 512];
#pragma unroll
    for (int kh = 0; kh < 2; ++kh) {
      short8 af[MI], bf[NJ];
#pragma unroll
      for (int i = 0; i < MI; ++i) {
        int R = wm + i * 16 + l15;
        af[i] = *(const short8*)(As + R * 64 +
                                 ((kh * 32 + quad * 8) ^ ((R & 7) * 8)));
      }
#pragma unroll
      for (int j = 0; j < NJ; ++j) {
        int R = wn + j * 16 + l15;
        bf[j] = *(const short8*)(Bs + R * 64 +
                                 ((kh * 32 + quad * 8) ^ ((R & 7) * 8)));
      }
#pragma unroll
      for (int i = 0; i < MI; ++i)
#pragma unroll
        for (int j = 0; j < NJ; ++j)
          acc[i][j] = __builtin_amdgcn_mfma_f32_16x16x32_bf16(af[i], bf[j],
                                                              acc[i][j], 0, 0, 0);
    }
  }

  float bv[NJ];
#pragma unroll
  for (int j = 0; j < NJ; ++j) bv[j] = bias[n0 + wn + j * 16 + l15];
#pragma unroll
  for (int i = 0; i < MI; ++i)
#pragma unroll
    for (int j = 0; j < NJ; ++j) {
      int col = n0 + wn + j * 16 + l15;
      bool doq = QSC && (col < 1024);
#pragma unroll
      for (int r = 0; r < 4; ++r) {
        int row = m0 + wm + i * 16 + quad * 4 + r;
        float val = acc[i][j][r] + bv[j];
        if (doq) val *= QSCALE_F;
        if (OUT_F32)
          ((float*)Cout)[(size_t)row * N + col] = val;
        else
          ((u16*)Cout)[(size_t)row * N + col] = f2bf(val);
      }
    }
}

// ---- flash attention: 16-wave blocks, strip-parallel waves ------------------
// R12: 1024 threads = 2 halves (kt parity) x 2 strips x 4 wq. Each wave owns
// 32 q rows of ONE supertile of the pair {15-p, p} -> the old per-wave t-loop
// runs in PARALLEL across waves; barrier interval = one strip's chain.
// waves/SIMD = 4 (was 2). Staging unchanged: strip-0 waves of each half are
// the stagers (256 threads/half, same as R11); no duplication (R10's bug).
// LDS 144 KB: K 3buf x 2half (48K) | V 2buf x 2half (32K) | P 16 x 4K (64K).
// Q pre-scaled (gemm1), QK acc init -16, lsum via mfma(ones,..) (R11).

__global__ __launch_bounds__(1024, 1) void flash_kernel(
    const u16* __restrict__ qkv, u16* __restrict__ att) {
  __shared__ unsigned int SH[36864];  // 144 KB

  int tid = threadIdx.x;
  int w = tid >> 6;
  int half = w >> 3;           // kt parity
  int strip = (w >> 2) & 1;    // which supertile of the pair
  int wq = w & 3;
  int lane = tid & 63, l15 = lane & 15, quad = lane >> 4;
  int bx = blockIdx.x;
  int p = bx >> 5, bh = bx & 31, b = bh >> 4, h = bh & 15;
  const int st = strip ? p : (15 - p);   // own supertile
  const int km = 2 * st + 1;             // last kt for own strip
  const int jmax = 16 - p;

  const u16* base = qkv + (size_t)b * 2048 * 3072 + h * 64;
  const u16* kb = base + 1024;
  const u16* vb = base + 2048;

  const bool stager = (strip == 0);      // waves 0-3 (h0), 8-11 (h1)
  int ht = tid & 255;
  const int krow = ht >> 3, h7 = ht & 7;
  const int swk = (h7 ^ (krow & 7)) * 8;  // swizzled K source col (u16)

  // persistent Q fragments [qsub][ss] (16 VGPRs)
  short8 qf[2][2];
  {
    const u16* qtb = base + (size_t)(st * 128 + wq * 32 + l15) * 3072;
    qf[0][0] = *(const short8*)(qtb + quad * 8);
    qf[0][1] = *(const short8*)(qtb + 32 + quad * 8);
    qf[1][0] = *(const short8*)(qtb + 16 * 3072 + quad * 8);
    qf[1][1] = *(const short8*)(qtb + 16 * 3072 + 32 + quad * 8);
  }

  // prologue: stagers DMA K tile 0 (kt=half) into Ks buf0, V tile 0 to regs
  uint4 vr0, vr1;
  if (stager) {
    unsigned int* Ks0 = SH + half * 2048;
    gl_lds16(kb + (size_t)(half * 64 + krow) * 3072 + swk,
             (char*)Ks0 + wq * 1024);
    gl_lds16(kb + (size_t)(half * 64 + 32 + krow) * 3072 + swk,
             (char*)Ks0 + 4096 + wq * 1024);
    vr0 = *(const uint4*)(vb + (size_t)(half * 64 + 2 * krow) * 3072 + h7 * 8);
    vr1 = *(const uint4*)(vb + (size_t)(half * 64 + 2 * krow + 1) * 3072 + h7 * 8);
  }

  f32x4 o[2][4];
#pragma unroll
  for (int qsub = 0; qsub < 2; ++qsub)
#pragma unroll
    for (int jd = 0; jd < 4; ++jd) {
      f32x4 z = {0.f, 0.f, 0.f, 0.f};
      o[qsub][jd] = z;
    }
  f32x4 l4[2];
#pragma unroll
  for (int qsub = 0; qsub < 2; ++qsub) {
    f32x4 z = {0.f, 0.f, 0.f, 0.f};
    l4[qsub] = z;
  }
  const short8 ones = {(short)0x3F80, (short)0x3F80, (short)0x3F80,
                       (short)0x3F80, (short)0x3F80, (short)0x3F80,
                       (short)0x3F80, (short)0x3F80};

  const int psw = (l15 & 7) << 2;
  unsigned int* Pw = SH + 20480 + w * 1024;

  int b3 = 0;
  for (int j = 0; j < jmax; ++j) {
    int kt = 2 * j + half;
    unsigned int* KsH = SH + b3 * 4096 + half * 2048;
    unsigned int* VtH = SH + 12288 + (j & 1) * 4096 + half * 2048;
    int nb3 = b3 + 1;
    if (nb3 == 3) nb3 = 0;

    if (stager) {
      // V pack tile j; first vr use drains tile j's K-DMA + V loads
      const u16* av = (const u16*)&vr0;
      const u16* bvp = (const u16*)&vr1;
#pragma unroll
      for (int jj = 0; jj < 8; ++jj) {
        int d = h7 * 8 + jj;
        VtH[32 * d + (krow ^ ((jj ^ h7) << 2))] =
            (unsigned int)av[jj] | ((unsigned int)bvp[jj] << 16);
      }
      if (j + 1 < jmax) {  // prefetch tile j+1: K via DMA, V into regs
        int kn = (kt + 2) * 64;
        unsigned int* Ksn = SH + nb3 * 4096 + half * 2048;
        gl_lds16(kb + (size_t)(kn + krow) * 3072 + swk,
                 (char*)Ksn + wq * 1024);
        gl_lds16(kb + (size_t)(kn + 32 + krow) * 3072 + swk,
                 (char*)Ksn + 4096 + wq * 1024);
        vr0 = *(const uint4*)(vb + (size_t)(kn + 2 * krow) * 3072 + h7 * 8);
        vr1 = *(const uint4*)(vb + (size_t)(kn + 2 * krow + 1) * 3072 + h7 * 8);
      }
    }
    b3 = nb3;

    asm volatile("s_waitcnt lgkmcnt(0)" ::: "memory");
    __builtin_amdgcn_s_barrier();
    asm volatile("" ::: "memory");

    if (kt > km) continue;               // strip done (wave-uniform)
    bool last = (kt == km);
    if (last && wq < 2) continue;        // fully-masked waves at final tile
    bool domask = last || ((kt == km - 1) && wq < 2);
    int qloc = ((last ? (wq - 2) : wq) << 5) + l15;  // valid when domask

    // S^T = K Q^T for both qsubs; acc init -16 = softmax shift.
    f32x4 s0[4], s1[4];
#pragma unroll
    for (int jn = 0; jn < 4; ++jn) {
      f32x4 z = {-16.f, -16.f, -16.f, -16.f};
      s0[jn] = z;
      s1[jn] = z;
    }
    __builtin_amdgcn_s_setprio(1);
#pragma unroll
    for (int ss = 0; ss < 2; ++ss) {
      short8 a0 = qf[0][ss];
      short8 a1 = qf[1][ss];
#pragma unroll
      for (int jn = 0; jn < 4; ++jn) {
        int row = jn * 16 + l15;
        short8 bk = *(const short8*)&KsH[32 * row + ((16 * ss + 4 * quad) ^
                                                     ((row & 7) << 2))];
        s0[jn] = __builtin_amdgcn_mfma_f32_16x16x32_bf16(bk, a0, s0[jn], 0, 0, 0);
        s1[jn] = __builtin_amdgcn_mfma_f32_16x16x32_bf16(bk, a1, s1[jn], 0, 0, 0);
      }
    }
    __builtin_amdgcn_s_setprio(0);

    // P = exp2(S) directly; mask only on causal-boundary tiles
#pragma unroll
    for (int qsub = 0; qsub < 2; ++qsub) {
      int qq = qloc + qsub * 16;
      float pvv[4][4];
      if (domask) {
#pragma unroll
        for (int jn = 0; jn < 4; ++jn) {
          f32x4 sv = qsub ? s1[jn] : s0[jn];
#pragma unroll
          for (int r = 0; r < 4; ++r) {
            float e = exp2_fast(sv[r]);
            if (jn * 16 + quad * 4 + r > qq) e = 0.f;
            pvv[jn][r] = e;
          }
        }
      } else {
#pragma unroll
        for (int jn = 0; jn < 4; ++jn) {
          f32x4 sv = qsub ? s1[jn] : s0[jn];
#pragma unroll
          for (int r = 0; r < 4; ++r)
            pvv[jn][r] = exp2_fast(sv[r]);
        }
      }
#pragma unroll
      for (int jn = 0; jn < 4; ++jn) {
        uint2 dd = make_uint2(pack_bf2(pvv[jn][0], pvv[jn][1]),
                              pack_bf2(pvv[jn][2], pvv[jn][3]));
        *(uint2*)&Pw[qsub * 512 + 32 * l15 +
                     (((jn << 3) + (quad << 1)) ^ psw)] = dd;
      }
    }

    // O^T += Vt P^T; row-sum via mfma(ones, pf, l4)
    __builtin_amdgcn_s_setprio(1);
#pragma unroll
    for (int ss = 0; ss < 2; ++ss) {
      short8 pf0 = *(const short8*)&Pw[32 * l15 +
                                       (((ss << 4) + (quad << 2)) ^ psw)];
      short8 pf1 = *(const short8*)&Pw[512 + 32 * l15 +
                                       (((ss << 4) + (quad << 2)) ^ psw)];
      l4[0] = __builtin_amdgcn_mfma_f32_16x16x32_bf16(ones, pf0, l4[0], 0, 0, 0);
      l4[1] = __builtin_amdgcn_mfma_f32_16x16x32_bf16(ones, pf1, l4[1], 0, 0, 0);
#pragma unroll
      for (int jd = 0; jd < 4; ++jd) {
        int vrow = jd * 16 + l15;
        int f = (vrow & 7) ^ ((vrow >> 3) & 7);
        short8 bvv = *(const short8*)&VtH[32 * vrow +
                                          (((ss << 4) + (quad << 2)) ^ (f << 2))];
        o[0][jd] =
            __builtin_amdgcn_mfma_f32_16x16x32_bf16(bvv, pf0, o[0][jd], 0, 0, 0);
        o[1][jd] =
            __builtin_amdgcn_mfma_f32_16x16x32_bf16(bvv, pf1, o[1][jd], 0, 0, 0);
      }
    }
    __builtin_amdgcn_s_setprio(0);
  }

  // denominator: every l4 slot holds the full row-sum
  float lf[2] = {l4[0][0], l4[1][0]};

  // ---- merge halves in LDS (partials additive under fixed shift) ----
  float* OM = (float*)SH;                 // [2 strips][128 q][68]
  float* LM = (float*)(SH + 17408);       // [2][128]
  __syncthreads();
  if (half == 0) {
#pragma unroll
    for (int qsub = 0; qsub < 2; ++qsub) {
      int q = wq * 32 + qsub * 16 + l15;
#pragma unroll
      for (int jd = 0; jd < 4; ++jd)
        *(float4*)&OM[(strip * 128 + q) * 68 + jd * 16 + quad * 4] =
            *(float4*)&o[qsub][jd];
      if (quad == 0) LM[strip * 128 + q] = lf[qsub];
    }
  }
  __syncthreads();
  if (half == 1) {
#pragma unroll
    for (int qsub = 0; qsub < 2; ++qsub) {
      int q = wq * 32 + qsub * 16 + l15;
      float lr = lf[qsub] + LM[strip * 128 + q];
      float inv = 1.f / lr;
      size_t row = (size_t)b * 2048 + st * 128 + q;
      u16* orow = att + row * 1024 + h * 64 + quad * 4;
#pragma unroll
      for (int jd = 0; jd < 4; ++jd) {
        float4 pa = *(float4*)&OM[(strip * 128 + q) * 68 + jd * 16 + quad * 4];
        uint2 dd = make_uint2(pack_bf2((o[0 + qsub][jd][0] + pa.x) * inv,
                                       (o[qsub][jd][1] + pa.y) * inv),
                              pack_bf2((o[qsub][jd][2] + pa.z) * inv,
                                       (o[qsub][jd][3] + pa.w) * inv));
        *(uint2*)(orow + jd * 16) = dd;
      }
    }
  }
}

// ---- launch ----------------------------------------------------------------

extern "C" void kernel_launch(void* const* d_in, const int* in_sizes, int n_in,
                              void* d_out, int out_size, void* d_ws,
                              size_t ws_size, hipStream_t stream) {
  const float* x = (const float*)d_in[0];
  const float* Wqkv = (const float*)d_in[1];
  const float* bqkv = (const float*)d_in[2];
  const float* Wout = (const float*)d_in[3];
  const float* bout = (const float*)d_in[4];
  float* out = (float*)d_out;

  char* ws = (char*)d_ws;
  u16* WqkvT = (u16*)(ws);            // [3072][1024] bf16
  u16* WoutT = (u16*)(ws + 6291456);  // [1024][1024] bf16
  u16* qkv = (u16*)(ws + 8388608);    // [4096][3072] bf16
  u16* attn = (u16*)(ws + 33554432);  // [4096][1024] bf16
  u16* xb = (u16*)(ws + 41943040);    // [4096][1024] bf16

  prep_kernel<<<5120, 256, 0, stream>>>((const float4*)x, (u16x4*)xb, Wqkv,
                                        WqkvT, Wout, WoutT);
  gemm8_kernel<false, 256, 192, true><<<dim3(16, 16), 512, 0, stream>>>(
      xb, WqkvT, bqkv, (void*)qkv, 4096, 3072, 1024);
  flash_kernel<<<256, 1024, 0, stream>>>(qkv, attn);
  gemm8_kernel<true, 128, 128, false><<<dim3(8, 32), 512, 0, stream>>>(
      attn, WoutT, bout, (void*)out, 4096, 1024, 1024);
}

// Round 13
// 159.439 us; speedup vs baseline: 1.2743x; 1.2743x over previous
//
#include <hip/hip_runtime.h>
#include <hip/hip_bf16.h>

typedef unsigned short u16;
typedef __attribute__((ext_vector_type(8))) short short8;
typedef __attribute__((ext_vector_type(4))) float f32x4;
typedef __attribute__((ext_vector_type(4))) unsigned short u16x4;

#define LOG2E 1.44269504088896340736f
// Q pre-scale: 1/sqrt(64) * log2(e), folded into the QKV gemm epilogue
#define QSCALE_F 0.18033688011112042f

// ---- helpers ---------------------------------------------------------------

__device__ __forceinline__ void gl_lds16(const void* g, void* l) {
  __builtin_amdgcn_global_load_lds(
      (__attribute__((address_space(1))) void*)g,
      (__attribute__((address_space(3))) void*)l, 16, 0, 0);
}

__device__ __forceinline__ float exp2_fast(float x) {
#if __has_builtin(__builtin_amdgcn_exp2f)
  return __builtin_amdgcn_exp2f(x);  // bare v_exp_f32
#else
  return exp2f(x);
#endif
}

__device__ __forceinline__ u16 f2bf(float f) {
  union { float f; unsigned int i; } v;
  v.f = f;
  unsigned int r = v.i + 0x7fffu + ((v.i >> 16) & 1u);  // RNE
  return (u16)(r >> 16);
}

__device__ __forceinline__ unsigned int pack_bf2(float lo, float hi) {
  union { __hip_bfloat162 h2; unsigned int u; } c;
  c.h2 = __float22bfloat162_rn(make_float2(lo, hi));
  return c.u;
}

// ---- fused prep: x->bf16 cvt + both weight transposes ----------------------

__global__ __launch_bounds__(256) void prep_kernel(
    const float4* __restrict__ x, u16x4* __restrict__ xb,
    const float* __restrict__ Wqkv, u16* __restrict__ WqkvT,
    const float* __restrict__ Wout, u16* __restrict__ WoutT) {
  __shared__ u16 t[64][65];
  int bid = blockIdx.x, tid = threadIdx.x;
  if (bid < 4096) {
    int i = bid * 256 + tid;
    float4 v = x[i];
    u16x4 o;
    o.x = f2bf(v.x); o.y = f2bf(v.y); o.z = f2bf(v.z); o.w = f2bf(v.w);
    xb[i] = o;
    return;
  }
  const float* W;
  u16* WT;
  int K = 1024, N, bxx, byy;
  if (bid < 4864) {
    int tt = bid - 4096;
    W = Wqkv; WT = WqkvT; N = 3072; bxx = tt % 48; byy = tt / 48;
  } else {
    int tt = bid - 4864;
    W = Wout; WT = WoutT; N = 1024; bxx = tt % 16; byy = tt / 16;
  }
  int r0 = byy * 64, c0 = bxx * 64;
  int tx = tid & 63, ty = tid >> 6;
  for (int r = ty; r < 64; r += 4)
    t[r][tx] = f2bf(W[(size_t)(r0 + r) * N + c0 + tx]);
  __syncthreads();
  for (int r = ty; r < 64; r += 4)
    WT[(size_t)(c0 + r) * K + r0 + tx] = t[tx][r];
}

// ---- gemm8: BMxBN tile, BK=64, 8 waves (2Mx4N), double-buffered LDS --------
// One barrier per K-tile: vmcnt(0); s_barrier; DMA tile t+1; compute tile t.
// DMA uses swizzle-precomputed SOURCE cols so lane-linear writes land
// XOR-swizzled; frag reads use addr ^ ((row&7)*8) -> conflict-free b128.
// Grids are exactly 256 blocks; bijective XCD swizzle (bid&7)*32+(bid>>3).
// QSC: scale output cols < 1024 (the Q block of the QKV gemm) by QSCALE_F so
// flash's softmax needs no per-element fmaf (acc-init -16 supplies the shift).

template <bool OUT_F32, int BM, int BN, bool QSC>
__global__ __launch_bounds__(512, 1) void gemm8_kernel(
    const u16* __restrict__ A, const u16* __restrict__ Bt,
    const float* __restrict__ bias, void* __restrict__ Cout,
    int M, int N, int K) {
  constexpr int MI = BM / 32;          // M frags per wave (BM/2 rows / 16)
  constexpr int NJ = BN / 64;          // N frags per wave (BN/4 cols / 16)
  constexpr int CH_A = BM / 8;         // 8-row staging chunks of A
  constexpr int CH_B = BN / 8;
  constexpr int PER_W = (CH_A + CH_B) / 8;  // chunks per wave
  __shared__ u16 LDS[2][(BM + BN) * 64];
  int tid = threadIdx.x;
  int w = tid >> 6, lane = tid & 63, l15 = lane & 15, quad = lane >> 4;
  // XCD-aware bijective swizzle (nwg == 256, divisible by 8)
  int bid = blockIdx.y * gridDim.x + blockIdx.x;
  int swz = ((bid & 7) << 5) | (bid >> 3);
  int bx = swz % gridDim.x, by = swz / gridDim.x;
  int m0 = by * BM, n0 = bx * BN;
  int wm = (w & 1) * (BM / 2), wn = (w >> 1) * (BN / 4);

  f32x4 acc[MI][NJ];
#pragma unroll
  for (int i = 0; i < MI; ++i)
#pragma unroll
    for (int j = 0; j < NJ; ++j) {
      f32x4 z = {0.f, 0.f, 0.f, 0.f};
      acc[i][j] = z;
    }

  int r8 = lane >> 3;                 // row within 8-row chunk
  int sw = ((lane & 7) ^ r8) * 8;     // swizzled source col (u16)

  // per-wave staging chunk list (fully unrolled -> stays in registers)
  const u16* srcp[PER_W];
  int dsto[PER_W];
#pragma unroll
  for (int i = 0; i < PER_W; ++i) {
    int c = w * PER_W + i;
    if (c < CH_A) {
      srcp[i] = A + (size_t)(m0 + c * 8 + r8) * K + sw;
    } else {
      srcp[i] = Bt + (size_t)(n0 + (c - CH_A) * 8 + r8) * K + sw;
    }
    dsto[i] = c * 512;
  }

  int nt = K >> 6;
  // prologue: stage tile 0 into buf 0
#pragma unroll
  for (int i = 0; i < PER_W; ++i) gl_lds16(srcp[i], &LDS[0][dsto[i]]);

  for (int t = 0; t < nt; ++t) {
    asm volatile("s_waitcnt vmcnt(0)" ::: "memory");
    __builtin_amdgcn_s_barrier();
    asm volatile("" ::: "memory");
    int cur = t & 1;
    if (t + 1 < nt) {
      int koff = (t + 1) << 6;
#pragma unroll
      for (int i = 0; i < PER_W; ++i)
        gl_lds16(srcp[i] + koff, &LDS[cur ^ 1][dsto[i]]);
    }
    const u16* As = &LDS[cur][0];
    const u16* Bs = &LDS[cur][CH_A * 512];
#pragma unroll
    for (int kh = 0; kh < 2; ++kh) {
      short8 af[MI], bf[NJ];
#pragma unroll
      for (int i = 0; i < MI; ++i) {
        int R = wm + i * 16 + l15;
        af[i] = *(const short8*)(As + R * 64 +
                                 ((kh * 32 + quad * 8) ^ ((R & 7) * 8)));
      }
#pragma unroll
      for (int j = 0; j < NJ; ++j) {
        int R = wn + j * 16 + l15;
        bf[j] = *(const short8*)(Bs + R * 64 +
                                 ((kh * 32 + quad * 8) ^ ((R & 7) * 8)));
      }
#pragma unroll
      for (int i = 0; i < MI; ++i)
#pragma unroll
        for (int j = 0; j < NJ; ++j)
          acc[i][j] = __builtin_amdgcn_mfma_f32_16x16x32_bf16(af[i], bf[j],
                                                              acc[i][j], 0, 0, 0);
    }
  }

  float bv[NJ];
#pragma unroll
  for (int j = 0; j < NJ; ++j) bv[j] = bias[n0 + wn + j * 16 + l15];
#pragma unroll
  for (int i = 0; i < MI; ++i)
#pragma unroll
    for (int j = 0; j < NJ; ++j) {
      int col = n0 + wn + j * 16 + l15;
      bool doq = QSC && (col < 1024);
#pragma unroll
      for (int r = 0; r < 4; ++r) {
        int row = m0 + wm + i * 16 + quad * 4 + r;
        float val = acc[i][j][r] + bv[j];
        if (doq) val *= QSCALE_F;
        if (OUT_F32)
          ((float*)Cout)[(size_t)row * N + col] = val;
        else
          ((u16*)Cout)[(size_t)row * N + col] = f2bf(val);
      }
    }
}

// ---- flash attention: paired 128-row q-supertiles + wave-split-K -----------
// R13 = R11 exactly (best measured, 159.7 us): 1 raw barrier/iter, persistent
// Q, triple-buffered K DMA, double-buffered V^T reg-staging, counted-wait
// pipeline, wave-uniform domask, setprio on MFMA clusters, Q pre-scaled +
// acc-init -16 (no per-element fmaf), lsum via mfma(ones, pf, l4).
// Structural plateau: 5 redesigns (dual-strip/V-pretranspose/in-reg-P/
// block-split/wave-split) all regressed; occupancy is boxed by LDS (112KB ->
// 1 block/CU) and VGPR (4 waves/SIMD spills). Remaining idle is the
// irreducible QK->exp->P->PV chain at 2 waves/SIMD.

__global__ __launch_bounds__(512, 2) void flash_kernel(
    const u16* __restrict__ qkv, u16* __restrict__ att) {
  __shared__ unsigned int SH[28672];  // 112 KB

  int tid = threadIdx.x;
  int w = tid >> 6, half = w >> 2, wq = w & 3;
  int lane = tid & 63, l15 = lane & 15, quad = lane >> 4;
  int bx = blockIdx.x;
  int p = bx >> 5, bh = bx & 31, b = bh >> 4, h = bh & 15;
  const int qs[2] = {15 - p, p};
  const int kmax0 = 2 * qs[0] + 1, kmax1 = 2 * p + 1;
  const int jmax = 16 - p;

  const u16* base = qkv + (size_t)b * 2048 * 3072 + h * 64;
  const u16* kb = base + 1024;
  const u16* vb = base + 2048;

  int ht = tid & 255;
  const int krow = ht >> 3, h7 = ht & 7;
  const int swk = (h7 ^ (krow & 7)) * 8;  // swizzled K source col (u16)

  // persistent Q fragments [t][qsub][ss] (32 VGPRs)
  short8 qf[2][2][2];
#pragma unroll
  for (int t = 0; t < 2; ++t) {
    const u16* qtb = base + (size_t)(qs[t] * 128 + wq * 32 + l15) * 3072;
    qf[t][0][0] = *(const short8*)(qtb + quad * 8);
    qf[t][0][1] = *(const short8*)(qtb + 32 + quad * 8);
    qf[t][1][0] = *(const short8*)(qtb + 16 * 3072 + quad * 8);
    qf[t][1][1] = *(const short8*)(qtb + 16 * 3072 + 32 + quad * 8);
  }

  // prologue: async-DMA K tile 0 (kt=half) into Ks buf0, V tile 0 into regs
  {
    unsigned int* Ks0 = SH + half * 2048;
    gl_lds16(kb + (size_t)(half * 64 + krow) * 3072 + swk,
             (char*)Ks0 + wq * 1024);
    gl_lds16(kb + (size_t)(half * 64 + 32 + krow) * 3072 + swk,
             (char*)Ks0 + 4096 + wq * 1024);
  }
  uint4 vr0 = *(const uint4*)(vb + (size_t)(half * 64 + 2 * krow) * 3072 + h7 * 8);
  uint4 vr1 = *(const uint4*)(vb + (size_t)(half * 64 + 2 * krow + 1) * 3072 + h7 * 8);

  f32x4 o[2][2][4];
#pragma unroll
  for (int t = 0; t < 2; ++t)
#pragma unroll
    for (int qsub = 0; qsub < 2; ++qsub)
#pragma unroll
      for (int jd = 0; jd < 4; ++jd) {
        f32x4 z = {0.f, 0.f, 0.f, 0.f};
        o[t][qsub][jd] = z;
      }
  // row-sum accumulators (every slot identical; slot 0 read at the end)
  f32x4 l4[2][2];
#pragma unroll
  for (int t = 0; t < 2; ++t)
#pragma unroll
    for (int qsub = 0; qsub < 2; ++qsub) {
      f32x4 z = {0.f, 0.f, 0.f, 0.f};
      l4[t][qsub] = z;
    }
  const short8 ones = {(short)0x3F80, (short)0x3F80, (short)0x3F80,
                       (short)0x3F80, (short)0x3F80, (short)0x3F80,
                       (short)0x3F80, (short)0x3F80};

  const int psw = (l15 & 7) << 2;
  unsigned int* Pw = SH + 20480 + w * 1024;

  int b3 = 0;
  for (int j = 0; j < jmax; ++j) {
    int kt = 2 * j + half;
    unsigned int* KsH = SH + b3 * 4096 + half * 2048;
    unsigned int* VtH = SH + 12288 + (j & 1) * 4096 + half * 2048;

    // stage V^T from regs (transpose+pack); first use of vr* forces the
    // vmcnt drain of tile j's K-DMA + V loads (issued one full iter ago)
    {
      const u16* av = (const u16*)&vr0;
      const u16* bvp = (const u16*)&vr1;
#pragma unroll
      for (int jj = 0; jj < 8; ++jj) {
        int d = h7 * 8 + jj;
        VtH[32 * d + (krow ^ ((jj ^ h7) << 2))] =
            (unsigned int)av[jj] | ((unsigned int)bvp[jj] << 16);
      }
    }

    int nb3 = b3 + 1;
    if (nb3 == 3) nb3 = 0;
    if (j + 1 < jmax) {  // prefetch tile j+1: K via DMA, V into regs
      int kn = (kt + 2) * 64;
      unsigned int* Ksn = SH + nb3 * 4096 + half * 2048;
      gl_lds16(kb + (size_t)(kn + krow) * 3072 + swk, (char*)Ksn + wq * 1024);
      gl_lds16(kb + (size_t)(kn + 32 + krow) * 3072 + swk,
               (char*)Ksn + 4096 + wq * 1024);
      vr0 = *(const uint4*)(vb + (size_t)(kn + 2 * krow) * 3072 + h7 * 8);
      vr1 = *(const uint4*)(vb + (size_t)(kn + 2 * krow + 1) * 3072 + h7 * 8);
    }
    b3 = nb3;

    // single barrier per iter: only drain LDS writes; keep the just-issued
    // tile j+1 loads (vmcnt) in flight across the barrier
    asm volatile("s_waitcnt lgkmcnt(0)" ::: "memory");
    __builtin_amdgcn_s_barrier();
    asm volatile("" ::: "memory");

#pragma unroll
    for (int t = 0; t < 2; ++t) {
      int km = t ? kmax1 : kmax0;
      if (kt > km) continue;               // strip done (wave-uniform)
      bool last = (kt == km);
      if (last && wq < 2) continue;        // fully-masked waves at final tile
      bool domask = last || ((kt == km - 1) && wq < 2);
      int qloc = ((last ? (wq - 2) : wq) << 5) + l15;  // valid when domask

      // S^T = K Q^T for both subtiles; acc init -16 = softmax shift.
      f32x4 s0[4], s1[4];
#pragma unroll
      for (int jn = 0; jn < 4; ++jn) {
        f32x4 z = {-16.f, -16.f, -16.f, -16.f};
        s0[jn] = z;
        s1[jn] = z;
      }
      __builtin_amdgcn_s_setprio(1);
#pragma unroll
      for (int ss = 0; ss < 2; ++ss) {
        short8 a0 = qf[t][0][ss];
        short8 a1 = qf[t][1][ss];
#pragma unroll
        for (int jn = 0; jn < 4; ++jn) {
          int row = jn * 16 + l15;
          short8 bk = *(const short8*)&KsH[32 * row + ((16 * ss + 4 * quad) ^
                                                       ((row & 7) << 2))];
          s0[jn] = __builtin_amdgcn_mfma_f32_16x16x32_bf16(bk, a0, s0[jn], 0, 0, 0);
          s1[jn] = __builtin_amdgcn_mfma_f32_16x16x32_bf16(bk, a1, s1[jn], 0, 0, 0);
        }
      }
      __builtin_amdgcn_s_setprio(0);

      // P = exp2(S) directly; mask only on causal-boundary tiles
#pragma unroll
      for (int qsub = 0; qsub < 2; ++qsub) {
        int qq = qloc + qsub * 16;
        float pvv[4][4];
        if (domask) {
#pragma unroll
          for (int jn = 0; jn < 4; ++jn) {
            f32x4 sv = qsub ? s1[jn] : s0[jn];
#pragma unroll
            for (int r = 0; r < 4; ++r) {
              float e = exp2_fast(sv[r]);
              if (jn * 16 + quad * 4 + r > qq) e = 0.f;
              pvv[jn][r] = e;
            }
          }
        } else {
#pragma unroll
          for (int jn = 0; jn < 4; ++jn) {
            f32x4 sv = qsub ? s1[jn] : s0[jn];
#pragma unroll
            for (int r = 0; r < 4; ++r)
              pvv[jn][r] = exp2_fast(sv[r]);
          }
        }
#pragma unroll
        for (int jn = 0; jn < 4; ++jn) {
          uint2 dd = make_uint2(pack_bf2(pvv[jn][0], pvv[jn][1]),
                                pack_bf2(pvv[jn][2], pvv[jn][3]));
          *(uint2*)&Pw[qsub * 512 + 32 * l15 +
                       (((jn << 3) + (quad << 1)) ^ psw)] = dd;
        }
      }

      // O^T += Vt P^T; each bvv read feeds 2 MFMAs.
      // Row-sum via mfma(ones, pf, l4): D = sum_k P[k][q] in every slot.
      __builtin_amdgcn_s_setprio(1);
#pragma unroll
      for (int ss = 0; ss < 2; ++ss) {
        short8 pf0 = *(const short8*)&Pw[32 * l15 +
                                         (((ss << 4) + (quad << 2)) ^ psw)];
        short8 pf1 = *(const short8*)&Pw[512 + 32 * l15 +
                                         (((ss << 4) + (quad << 2)) ^ psw)];
        l4[t][0] = __builtin_amdgcn_mfma_f32_16x16x32_bf16(ones, pf0,
                                                           l4[t][0], 0, 0, 0);
        l4[t][1] = __builtin_amdgcn_mfma_f32_16x16x32_bf16(ones, pf1,
                                                           l4[t][1], 0, 0, 0);
#pragma unroll
        for (int jd = 0; jd < 4; ++jd) {
          int vrow = jd * 16 + l15;
          int f = (vrow & 7) ^ ((vrow >> 3) & 7);
          short8 bvv = *(const short8*)&VtH[32 * vrow +
                                            (((ss << 4) + (quad << 2)) ^ (f << 2))];
          o[t][0][jd] =
              __builtin_amdgcn_mfma_f32_16x16x32_bf16(bvv, pf0, o[t][0][jd], 0, 0, 0);
          o[t][1][jd] =
              __builtin_amdgcn_mfma_f32_16x16x32_bf16(bvv, pf1, o[t][1][jd], 0, 0, 0);
        }
      }
      __builtin_amdgcn_s_setprio(0);
    }
  }

  // denominator per (t,qsub): every l4 slot holds the full row-sum
  float lf[2][2];
#pragma unroll
  for (int t = 0; t < 2; ++t)
#pragma unroll
    for (int qsub = 0; qsub < 2; ++qsub) lf[t][qsub] = l4[t][qsub][0];

  // ---- merge halves in LDS (partials additive under fixed shift) ----
  float* OM = (float*)SH;            // [q=128][68]
  float* LM = (float*)(SH + 8704);   // [128]
  __syncthreads();
#pragma unroll
  for (int t = 0; t < 2; ++t) {
    if (half == 0) {
#pragma unroll
      for (int qsub = 0; qsub < 2; ++qsub) {
        int q = wq * 32 + qsub * 16 + l15;
#pragma unroll
        for (int jd = 0; jd < 4; ++jd)
          *(float4*)&OM[q * 68 + jd * 16 + quad * 4] = *(float4*)&o[t][qsub][jd];
        if (quad == 0) LM[q] = lf[t][qsub];
      }
    }
    __syncthreads();
    if (half == 1) {
#pragma unroll
      for (int qsub = 0; qsub < 2; ++qsub) {
        int q = wq * 32 + qsub * 16 + l15;
        float lr = lf[t][qsub] + LM[q];
        float inv = 1.f / lr;
        size_t row = (size_t)b * 2048 + qs[t] * 128 + q;
        u16* orow = att + row * 1024 + h * 64 + quad * 4;
#pragma unroll
        for (int jd = 0; jd < 4; ++jd) {
          float4 pa = *(float4*)&OM[q * 68 + jd * 16 + quad * 4];
          uint2 dd = make_uint2(pack_bf2((o[t][qsub][jd][0] + pa.x) * inv,
                                         (o[t][qsub][jd][1] + pa.y) * inv),
                                pack_bf2((o[t][qsub][jd][2] + pa.z) * inv,
                                         (o[t][qsub][jd][3] + pa.w) * inv));
          *(uint2*)(orow + jd * 16) = dd;
        }
      }
    }
    __syncthreads();
  }
}

// ---- launch ----------------------------------------------------------------

extern "C" void kernel_launch(void* const* d_in, const int* in_sizes, int n_in,
                              void* d_out, int out_size, void* d_ws,
                              size_t ws_size, hipStream_t stream) {
  const float* x = (const float*)d_in[0];
  const float* Wqkv = (const float*)d_in[1];
  const float* bqkv = (const float*)d_in[2];
  const float* Wout = (const float*)d_in[3];
  const float* bout = (const float*)d_in[4];
  float* out = (float*)d_out;

  char* ws = (char*)d_ws;
  u16* WqkvT = (u16*)(ws);            // [3072][1024] bf16
  u16* WoutT = (u16*)(ws + 6291456);  // [1024][1024] bf16
  u16* qkv = (u16*)(ws + 8388608);    // [4096][3072] bf16
  u16* attn = (u16*)(ws + 33554432);  // [4096][1024] bf16
  u16* xb = (u16*)(ws + 41943040);    // [4096][1024] bf16

  prep_kernel<<<5120, 256, 0, stream>>>((const float4*)x, (u16x4*)xb, Wqkv,
                                        WqkvT, Wout, WoutT);
  gemm8_kernel<false, 256, 192, true><<<dim3(16, 16), 512, 0, stream>>>(
      xb, WqkvT, bqkv, (void*)qkv, 4096, 3072, 1024);
  flash_kernel<<<256, 512, 0, stream>>>(qkv, attn);
  gemm8_kernel<true, 128, 128, false><<<dim3(8, 32), 512, 0, stream>>>(
      attn, WoutT, bout, (void*)out, 4096, 1024, 1024);
}